// Round 14
// baseline (336.138 us; speedup 1.0000x reference)
//
#include <hip/hip_runtime.h>
#include <hip/hip_fp16.h>
#include <math.h>

// ---------------------------------------------------------------------------
// GCN 3-layer forward. bf16 MFMA GEMM, fp16 gather payload, fp32 accumulate.
// Y contiguous [n+1][128] fp16 (pad-row n = zeros). All aggs unweighted:
//   gemm1 folds dinv into Y1; agg epilogue folds dinv into Hb (bf16) so
//   Y_l = Hb@W_l is pre-scaled for layers 2,3.
// CSR compact: rowptr = excl-scan of roundup8(deg); R7 rank trick (count's
// atomicAdd return = slot rank) -> atomic-free place.
// Floors (measured, multi-probe): count atomics ~23G/s at FULL occupancy;
// agg gather ~3.3TB/s LLC->L2 refill of 8-XCD x |Y| (byte-proportional,
// schedule-independent); GEMMs memory-bound. R14: scans 3->2 kernels via
// last-block-partial-scan (saves ~6us of launch+serial); rest frozen at R13.
// ---------------------------------------------------------------------------

#define BLK 256

typedef short bf16x8 __attribute__((ext_vector_type(8)));
typedef float f32x4 __attribute__((ext_vector_type(4)));

__device__ __forceinline__ unsigned short f2bf(float f) {
    unsigned int u = __float_as_uint(f);
    u += 0x7fffu + ((u >> 16) & 1u);
    return (unsigned short)(u >> 16);
}

__device__ __forceinline__ int sel4(const int4 v, int q) {
    return (q == 0) ? v.x : (q == 1) ? v.y : (q == 2) ? v.z : v.w;
}

__device__ __forceinline__ void acc8(float* __restrict__ acc, const __half* __restrict__ p) {
    uint4 u = *(const uint4*)p;
    const __half2* h = (const __half2*)&u;
    float2 f0 = __half22float2(h[0]);
    float2 f1 = __half22float2(h[1]);
    float2 f2 = __half22float2(h[2]);
    float2 f3 = __half22float2(h[3]);
    acc[0] += f0.x; acc[1] += f0.y; acc[2] += f1.x; acc[3] += f1.y;
    acc[4] += f2.x; acc[5] += f2.y; acc[6] += f3.x; acc[7] += f3.y;
}

// ---- megaA: [count+rank || colidx-init || Wt1/2/3 cast], all LDS-free -----
__global__ __launch_bounds__(256) void megaA(
    const int* __restrict__ dst, int* __restrict__ deg, int* __restrict__ rnk, int E,
    int* __restrict__ colidx, int Epad, int n,
    const float* __restrict__ W1, const float* __restrict__ W2, const float* __restrict__ W3,
    unsigned short* __restrict__ Wt1, unsigned short* __restrict__ Wt2,
    unsigned short* __restrict__ Wt3, int nCount, int nInit) {
    const int b = blockIdx.x, t = threadIdx.x;
    if (b < nCount) {
        int stride = nCount * 256;
        for (int e = b * 256 + t; e < E; e += stride)
            rnk[e] = atomicAdd(&deg[dst[e]], 1);     // 0-based rank
    } else if (b < nCount + nInit) {
        int bb = b - nCount;
        int4* c4 = (int4*)colidx;
        const int len4 = Epad >> 2;
        int4 v = make_int4(n, n, n, n);
        for (int i = bb * 256 + t; i < len4; i += nInit * 256) c4[i] = v;
    } else {
        int idx = (b - nCount - nInit) * 256 + t;
        if (idx < 16384) {
            int k = idx >> 7, c = idx & 127;
            Wt1[c * 128 + k] = f2bf(W1[idx]);
        } else if (idx < 32768) {
            int j = idx - 16384; int k = j >> 7, c = j & 127;
            Wt2[c * 128 + k] = f2bf(W2[j]);
        } else if (idx < 40960) {
            int j = idx - 32768; int k = j >> 6, c = j & 63;
            Wt3[c * 128 + k] = f2bf(W3[j]);
        }
    }
}

// ---- fused scan: per-block reduce of roundup8(deg) -> bsum; last block
// exclusive-scans bsum in place (flag pre-zeroed by the deg memset) ---------
__global__ __launch_bounds__(256) void scan_fuse(const int* __restrict__ deg,
                                                 int* __restrict__ bsum,
                                                 int* __restrict__ flag, int nb, int n) {
    __shared__ int s[BLK];
    __shared__ int isLast;
    int i = blockIdx.x * BLK + threadIdx.x;
    s[threadIdx.x] = (i < n) ? ((deg[i] + 7) & ~7) : 0;
    __syncthreads();
    for (int off = BLK / 2; off > 0; off >>= 1) {
        if (threadIdx.x < off) s[threadIdx.x] += s[threadIdx.x + off];
        __syncthreads();
    }
    if (threadIdx.x == 0) {
        bsum[blockIdx.x] = s[0];
        __threadfence();
        int v = atomicAdd(flag, 1);
        isLast = (v == nb - 1) ? 1 : 0;
    }
    __syncthreads();
    if (isLast) {
        __threadfence();                 // acquire: see all bsum writes
        __shared__ int a[512];
        __shared__ int b2[512];
        int t = threadIdx.x;
        int v0 = (t < nb) ? bsum[t] : 0;
        int v1 = (t + 256 < nb) ? bsum[t + 256] : 0;
        a[t] = v0; a[t + 256] = v1;
        __syncthreads();
        int* src = a; int* dst2 = b2;
        for (int off = 1; off < 512; off <<= 1) {
            int x0 = src[t];
            if (t >= off) x0 += src[t - off];
            int x1 = src[t + 256];
            if (t + 256 >= off) x1 += src[t + 256 - off];
            dst2[t] = x0; dst2[t + 256] = x1;
            __syncthreads();
            int* tmp = src; src = dst2; dst2 = tmp;
        }
        if (t < nb) bsum[t] = src[t] - v0;            // exclusive
        if (t + 256 < nb) bsum[t + 256] = src[t + 256] - v1;
    }
}

__global__ void scan_write_rowptr(const int* __restrict__ deg, const int* __restrict__ bsum,
                                  int* __restrict__ rowptr, float* __restrict__ dinv, int n) {
    __shared__ int a[BLK];
    __shared__ int b[BLK];
    int t = threadIdx.x;
    int i = blockIdx.x * BLK + t;
    int dgv = (i < n) ? deg[i] : 0;
    int v = (i < n) ? ((dgv + 7) & ~7) : 0;
    a[t] = v;
    __syncthreads();
    int* s = a; int* d = b;
    for (int off = 1; off < BLK; off <<= 1) {
        int val = s[t];
        if (t >= off) val += s[t - off];
        d[t] = val;
        __syncthreads();
        int* tmp = s; s = d; d = tmp;
    }
    if (i < n) {
        rowptr[i] = (s[t] - v) + bsum[blockIdx.x];
        dinv[i] = rsqrtf((float)(dgv + 1));
    }
}

// ---- GEMM body: Y[n+1][KOUT] fp16; optional dinv fold; pad-row n zeroed ---
template <int KOUT, bool HF32, bool FOLD>
__device__ __forceinline__ void gemm_body(int gb, const void* __restrict__ Hv,
                                          const unsigned short* __restrict__ Wt,
                                          const float* __restrict__ dinv,
                                          __half* __restrict__ Y, int n,
                                          unsigned short (*Hl)[72],
                                          unsigned short (*Wl)[72]) {
    const int t = threadIdx.x;
    const int row0 = gb * 64;
    const int wave = t >> 6, lane = t & 63;
    const int r16 = lane & 15, ko8 = (lane >> 4) * 8;

    if (gb == 0 && t < KOUT) Y[(size_t)n * KOUT + t] = __float2half(0.f);

    f32x4 acc[KOUT / 16];
#pragma unroll
    for (int c = 0; c < KOUT / 16; c++) acc[c] = (f32x4){0.f, 0.f, 0.f, 0.f};

#pragma unroll
    for (int h = 0; h < 2; h++) {
        if (h) __syncthreads();
        for (int idx = t; idx < KOUT * 8; idx += 256) {
            int r = idx >> 3, seg = idx & 7;
            *(uint4*)&Wl[r][seg * 8] = *(const uint4*)(Wt + r * 128 + h * 64 + seg * 8);
        }
        if (HF32) {
            const float* H = (const float*)Hv;
            for (int idx = t; idx < 64 * 8; idx += 256) {
                int r = idx >> 3, seg = idx & 7;
                int row = row0 + r;
                unsigned short tmp[8];
                if (row < n) {
                    const float* p = H + (size_t)row * 128 + h * 64 + seg * 8;
                    float4 v0 = *(const float4*)p, v1 = *(const float4*)(p + 4);
                    tmp[0] = f2bf(v0.x); tmp[1] = f2bf(v0.y); tmp[2] = f2bf(v0.z); tmp[3] = f2bf(v0.w);
                    tmp[4] = f2bf(v1.x); tmp[5] = f2bf(v1.y); tmp[6] = f2bf(v1.z); tmp[7] = f2bf(v1.w);
                } else {
#pragma unroll
                    for (int j = 0; j < 8; j++) tmp[j] = 0;
                }
                *(uint4*)&Hl[r][seg * 8] = *(const uint4*)tmp;
            }
        } else {
            const unsigned short* H = (const unsigned short*)Hv;
            for (int idx = t; idx < 64 * 8; idx += 256) {
                int r = idx >> 3, seg = idx & 7;
                int row = row0 + r;
                uint4 v = make_uint4(0, 0, 0, 0);
                if (row < n) v = *(const uint4*)(H + (size_t)row * 128 + h * 64 + seg * 8);
                *(uint4*)&Hl[r][seg * 8] = v;
            }
        }
        __syncthreads();
#pragma unroll
        for (int kc = 0; kc < 2; kc++) {
            bf16x8 a = *(const bf16x8*)&Hl[wave * 16 + r16][kc * 32 + ko8];
#pragma unroll
            for (int c = 0; c < KOUT / 16; c++) {
                bf16x8 bb = *(const bf16x8*)&Wl[c * 16 + r16][kc * 32 + ko8];
                acc[c] = __builtin_amdgcn_mfma_f32_16x16x32_bf16(a, bb, acc[c], 0, 0, 0);
            }
        }
    }

    const int mbase = row0 + wave * 16 + (lane >> 4) * 4;
#pragma unroll
    for (int r = 0; r < 4; r++) {
        int row = mbase + r;
        if (row < n) {
            float dv = FOLD ? dinv[row] : 1.f;
#pragma unroll
            for (int c = 0; c < KOUT / 16; c++)
                Y[(size_t)row * KOUT + c * 16 + r16] = __float2half_rn(acc[c][r] * dv);
        }
    }
}

// ---- megaB: [atomic-free place || gemm1 (x@Wt1, fold dinv)] ---------------
__global__ __launch_bounds__(256) void megaB(
    const int* __restrict__ src, const int* __restrict__ dst,
    const int* __restrict__ rnk, const int* __restrict__ rowptr,
    int* __restrict__ colidx, int E,
    const float* __restrict__ x, const unsigned short* __restrict__ Wt1,
    const float* __restrict__ dinv, __half* __restrict__ Y, int n, int nPlace) {
    __shared__ unsigned short Hl[64][72];
    __shared__ unsigned short Wl[128][72];
    const int b = blockIdx.x, t = threadIdx.x;
    if (b < nPlace) {
        int stride = nPlace * 256;
        for (int e = b * 256 + t; e < E; e += stride)
            colidx[rowptr[dst[e]] + rnk[e]] = src[e];
    } else {
        gemm_body<128, true, true>(b - nPlace, x, Wt1, dinv, Y, n, Hl, Wl);
    }
}

template <int KOUT>
__global__ __launch_bounds__(256) void gemm_std(const unsigned short* __restrict__ H,
                                                const unsigned short* __restrict__ Wt,
                                                __half* __restrict__ Y, int n) {
    __shared__ unsigned short Hl[64][72];
    __shared__ unsigned short Wl[KOUT][72];
    gemm_body<KOUT, false, false>(blockIdx.x, H, Wt, nullptr, Y, n, Hl, Wl);
}

// ---- agg KOUT=128 (R8 shape): quarter-wave per row, 4 edges/load-inst;
// Ys pre-scaled; epilogue relu + fold dinv -> bf16 Hb ----------------------
__global__ __launch_bounds__(256) void agg128(const __half* __restrict__ Ys,
                                              const int* __restrict__ deg,
                                              const float* __restrict__ dinv,
                                              const int* __restrict__ rowptr,
                                              const int* __restrict__ colidx,
                                              const float* __restrict__ bias,
                                              unsigned short* __restrict__ outb, int n) {
    int wid = (blockIdx.x * blockDim.x + threadIdx.x) >> 6;
    int lane = threadIdx.x & 63;
    if (wid >= n) return;
    const int q = lane >> 4;
    const int l4 = lane & 15;

    int start = __builtin_amdgcn_readfirstlane(rowptr[wid]);
    int m     = __builtin_amdgcn_readfirstlane(deg[wid]);   // indegree, no self
    int mpad  = (m + 7) & ~7;
    float di = dinv[wid];

    float acc[8];
#pragma unroll
    for (int j = 0; j < 8; j++) acc[j] = 0.f;
    if (q == 0) acc8(acc, Ys + ((size_t)wid << 7) + l4 * 8);  // self (pre-scaled)

    const int4* cp4 = (const int4*)(colidx + start);   // start % 8 == 0
    for (int j = 0; j < mpad; j += 8) {
        int4 a = cp4[j >> 2];
        int4 b = cp4[(j >> 2) + 1];
        int s0 = sel4(a, q), s1 = sel4(b, q);
        acc8(acc, Ys + ((size_t)s0 << 7) + l4 * 8);
        acc8(acc, Ys + ((size_t)s1 << 7) + l4 * 8);
    }
#pragma unroll
    for (int j = 0; j < 8; j++) {
        acc[j] += __shfl_xor(acc[j], 16);
        acc[j] += __shfl_xor(acc[j], 32);
    }

    if (q == 0) {
        float scale = di / (float)(m + 1);
        float4 b0 = *(const float4*)(bias + l4 * 8);
        float4 b1 = *(const float4*)(bias + l4 * 8 + 4);
        float o[8];
        o[0] = acc[0] * scale + b0.x; o[1] = acc[1] * scale + b0.y;
        o[2] = acc[2] * scale + b0.z; o[3] = acc[3] * scale + b0.w;
        o[4] = acc[4] * scale + b1.x; o[5] = acc[5] * scale + b1.y;
        o[6] = acc[6] * scale + b1.z; o[7] = acc[7] * scale + b1.w;
        unsigned short ob[8];
#pragma unroll
        for (int j = 0; j < 8; j++) ob[j] = f2bf(fmaxf(o[j], 0.f) * di);  // relu+fold
        *(uint4*)(outb + ((size_t)wid << 7) + l4 * 8) = *(const uint4*)ob;
    }
}

// ---- agg KOUT=64 (R8 shape): eighth-wave per row, 8 edges/load-inst; fp32 --
__global__ __launch_bounds__(256) void agg64(const __half* __restrict__ Ys,
                                             const int* __restrict__ deg,
                                             const float* __restrict__ dinv,
                                             const int* __restrict__ rowptr,
                                             const int* __restrict__ colidx,
                                             const float* __restrict__ bias,
                                             float* __restrict__ out, int n) {
    int wid = (blockIdx.x * blockDim.x + threadIdx.x) >> 6;
    int lane = threadIdx.x & 63;
    if (wid >= n) return;
    const int oct = lane >> 3;
    const int l3 = lane & 7;

    int start = __builtin_amdgcn_readfirstlane(rowptr[wid]);
    int m     = __builtin_amdgcn_readfirstlane(deg[wid]);
    int mpad  = (m + 7) & ~7;
    float di = dinv[wid];

    float acc[8];
#pragma unroll
    for (int j = 0; j < 8; j++) acc[j] = 0.f;
    if (oct == 0) acc8(acc, Ys + ((size_t)wid << 6) + l3 * 8);

    const int4* cp4 = (const int4*)(colidx + start);
    for (int j = 0; j < mpad; j += 8) {
        int4 a = cp4[j >> 2];
        int4 b = cp4[(j >> 2) + 1];
        int se = (oct < 4) ? sel4(a, oct) : sel4(b, oct - 4);
        acc8(acc, Ys + ((size_t)se << 6) + l3 * 8);
    }
#pragma unroll
    for (int j = 0; j < 8; j++) {
        acc[j] += __shfl_xor(acc[j], 8);
        acc[j] += __shfl_xor(acc[j], 16);
        acc[j] += __shfl_xor(acc[j], 32);
    }

    if (oct == 0) {
        float scale = di / (float)(m + 1);
        float4 b0 = *(const float4*)(bias + l3 * 8);
        float4 b1 = *(const float4*)(bias + l3 * 8 + 4);
        float o[8];
        o[0] = acc[0] * scale + b0.x; o[1] = acc[1] * scale + b0.y;
        o[2] = acc[2] * scale + b0.z; o[3] = acc[3] * scale + b0.w;
        o[4] = acc[4] * scale + b1.x; o[5] = acc[5] * scale + b1.y;
        o[6] = acc[6] * scale + b1.z; o[7] = acc[7] * scale + b1.w;
        float* op = out + ((size_t)wid << 6) + l3 * 8;
        *(float4*)op = make_float4(o[0], o[1], o[2], o[3]);
        *(float4*)(op + 4) = make_float4(o[4], o[5], o[6], o[7]);
    }
}

extern "C" void kernel_launch(void* const* d_in, const int* in_sizes, int n_in,
                              void* d_out, int out_size, void* d_ws, size_t ws_size,
                              hipStream_t stream) {
    const float* x  = (const float*)d_in[0];
    const int*   ei = (const int*)d_in[1];
    const float* W1 = (const float*)d_in[2];
    const float* b1 = (const float*)d_in[3];
    const float* W2 = (const float*)d_in[4];
    const float* b2 = (const float*)d_in[5];
    const float* W3 = (const float*)d_in[6];
    const float* b3 = (const float*)d_in[7];
    float* out = (float*)d_out;

    const int n = in_sizes[0] / 128;      // 100000
    const int E = in_sizes[1] / 2;        // 1600000
    const int* srcA = ei;
    const int* dstA = ei + E;
    const int Epad = E + 8 * n + 64;      // segments padded to 8 + slack

    // ---- workspace carve (aligned to 256B) ----
    auto alignup = [](size_t v) { return (v + 255) & ~(size_t)255; };
    char* base = (char*)d_ws;
    size_t off = 0;
    int* deg    = (int*)(base + off); off = alignup(off + (size_t)(n + 64) * 4);  // +flag room
    int* flag   = deg + n;                       // covered by the deg memset
    int* rnk    = (int*)(base + off); off = alignup(off + (size_t)E * 4);
    int* rowptr = (int*)(base + off); off = alignup(off + (size_t)n * 4);
    int* bsum   = (int*)(base + off); off = alignup(off + (size_t)1024 * 4);
    int* colidx = (int*)(base + off); off = alignup(off + (size_t)Epad * 4);
    float* dinv = (float*)(base + off); off = alignup(off + (size_t)n * 4);
    unsigned short* Wt1 = (unsigned short*)(base + off); off = alignup(off + 16384 * 2);
    unsigned short* Wt2 = (unsigned short*)(base + off); off = alignup(off + 16384 * 2);
    unsigned short* Wt3 = (unsigned short*)(base + off); off = alignup(off + 8192 * 2);
    unsigned short* Hb  = (unsigned short*)(base + off); off = alignup(off + (size_t)n * 128 * 2);
    __half* Yb  = (__half*)(base + off); off = alignup(off + (size_t)(n + 1) * 128 * 2);
    (void)ws_size;

    const int nbN = (n + BLK - 1) / BLK;             // 391
    const int nCount = 2048, nInit = 256, nCast = 160;   // count needs full occupancy
    const int nPlace = 1024;
    const int nGemm = (n + 63) / 64;                 // 1563
    const int aggBlocks = (n * 64 + BLK - 1) / BLK;  // wave per node

    hipMemsetAsync(deg, 0, (size_t)(n + 1) * 4, stream);   // deg + flag

    // A: [count+rank || colidx init || Wt cast] — all LDS-free
    megaA<<<nCount + nInit + nCast, 256, 0, stream>>>(
        dstA, deg, rnk, E, colidx, Epad, n, W1, W2, W3, Wt1, Wt2, Wt3, nCount, nInit);

    // fused scan (block sums + last-block partial scan), then rowptr+dinv
    scan_fuse<<<nbN, BLK, 0, stream>>>(deg, bsum, flag, nbN, n);
    scan_write_rowptr<<<nbN, BLK, 0, stream>>>(deg, bsum, rowptr, dinv, n);

    // B: [place || gemm1 (x@Wt1, dinv folded)]
    megaB<<<nPlace + nGemm, 256, 0, stream>>>(
        srcA, dstA, rnk, rowptr, colidx, E, x, Wt1, dinv, Yb, n, nPlace);

    // layer 1 agg -> Hb bf16 (relu + fold dinv)
    agg128<<<aggBlocks, BLK, 0, stream>>>(Yb, deg, dinv, rowptr, colidx, b1, Hb, n);

    // layer 2
    gemm_std<128><<<nGemm, 256, 0, stream>>>(Hb, Wt2, Yb, n);
    agg128<<<aggBlocks, BLK, 0, stream>>>(Yb, deg, dinv, rowptr, colidx, b2, Hb, n);

    // layer 3 (KOUT=64, fp32 out, no relu)
    gemm_std<64><<<nGemm, 256, 0, stream>>>(Hb, Wt3, Yb, n);
    agg64<<<aggBlocks, BLK, 0, stream>>>(Yb, deg, dinv, rowptr, colidx, b3, out, n);
}

// Round 15
// 327.996 us; speedup vs baseline: 1.0248x; 1.0248x over previous
//
#include <hip/hip_runtime.h>
#include <hip/hip_fp16.h>
#include <math.h>

// ---------------------------------------------------------------------------
// GCN 3-layer forward. bf16 MFMA GEMM, fp16 gather payload, fp32 accumulate.
// Y contiguous [n+1][128] fp16 (pad-row n = zeros). All aggs unweighted:
//   gemm1 folds dinv into Y1; agg epilogue folds dinv into Hb (bf16) so
//   Y_l = Hb@W_l is pre-scaled for layers 2,3.
// CSR compact: rowptr = excl-scan of roundup8(deg); R7 rank trick (count's
// atomicAdd return = slot rank) -> atomic-free place.
// Floors (measured, multi-probe): count atomics ~23G/s at FULL occupancy
// (R11/R13); agg gather ~3.3TB/s LLC->L2 refill of 8-XCD x |Y| (byte-
// proportional, schedule-independent, R3-R12); GEMMs memory-bound.
// R15 = R13 exact revert (R14's scan-fuse was neutral-to-negative: launch
// overhead ~2us/kernel, last-block drain ate the saving).
// ---------------------------------------------------------------------------

#define BLK 256

typedef short bf16x8 __attribute__((ext_vector_type(8)));
typedef float f32x4 __attribute__((ext_vector_type(4)));

__device__ __forceinline__ unsigned short f2bf(float f) {
    unsigned int u = __float_as_uint(f);
    u += 0x7fffu + ((u >> 16) & 1u);
    return (unsigned short)(u >> 16);
}

__device__ __forceinline__ int sel4(const int4 v, int q) {
    return (q == 0) ? v.x : (q == 1) ? v.y : (q == 2) ? v.z : v.w;
}

__device__ __forceinline__ void acc8(float* __restrict__ acc, const __half* __restrict__ p) {
    uint4 u = *(const uint4*)p;
    const __half2* h = (const __half2*)&u;
    float2 f0 = __half22float2(h[0]);
    float2 f1 = __half22float2(h[1]);
    float2 f2 = __half22float2(h[2]);
    float2 f3 = __half22float2(h[3]);
    acc[0] += f0.x; acc[1] += f0.y; acc[2] += f1.x; acc[3] += f1.y;
    acc[4] += f2.x; acc[5] += f2.y; acc[6] += f3.x; acc[7] += f3.y;
}

// ---- megaA: [count+rank || colidx-init || Wt1/2/3 cast], all LDS-free -----
__global__ __launch_bounds__(256) void megaA(
    const int* __restrict__ dst, int* __restrict__ deg, int* __restrict__ rnk, int E,
    int* __restrict__ colidx, int Epad, int n,
    const float* __restrict__ W1, const float* __restrict__ W2, const float* __restrict__ W3,
    unsigned short* __restrict__ Wt1, unsigned short* __restrict__ Wt2,
    unsigned short* __restrict__ Wt3, int nCount, int nInit) {
    const int b = blockIdx.x, t = threadIdx.x;
    if (b < nCount) {
        int stride = nCount * 256;
        for (int e = b * 256 + t; e < E; e += stride)
            rnk[e] = atomicAdd(&deg[dst[e]], 1);     // 0-based rank
    } else if (b < nCount + nInit) {
        int bb = b - nCount;
        int4* c4 = (int4*)colidx;
        const int len4 = Epad >> 2;
        int4 v = make_int4(n, n, n, n);
        for (int i = bb * 256 + t; i < len4; i += nInit * 256) c4[i] = v;
    } else {
        int idx = (b - nCount - nInit) * 256 + t;
        if (idx < 16384) {
            int k = idx >> 7, c = idx & 127;
            Wt1[c * 128 + k] = f2bf(W1[idx]);
        } else if (idx < 32768) {
            int j = idx - 16384; int k = j >> 7, c = j & 127;
            Wt2[c * 128 + k] = f2bf(W2[j]);
        } else if (idx < 40960) {
            int j = idx - 32768; int k = j >> 6, c = j & 63;
            Wt3[c * 128 + k] = f2bf(W3[j]);
        }
    }
}

// ---- scans: exclusive scan of roundup8(deg) into rowptr; dinv fused -------
__global__ void scan_block_sums(const int* __restrict__ deg, int* __restrict__ bsum, int n) {
    __shared__ int s[BLK];
    int i = blockIdx.x * BLK + threadIdx.x;
    s[threadIdx.x] = (i < n) ? ((deg[i] + 7) & ~7) : 0;
    __syncthreads();
    for (int off = BLK / 2; off > 0; off >>= 1) {
        if (threadIdx.x < off) s[threadIdx.x] += s[threadIdx.x + off];
        __syncthreads();
    }
    if (threadIdx.x == 0) bsum[blockIdx.x] = s[0];
}

__global__ void scan_partials_excl(int* __restrict__ bsum, int nb) {
    __shared__ int a[512];
    __shared__ int b[512];
    int t = threadIdx.x;
    int v = (t < nb) ? bsum[t] : 0;
    a[t] = v;
    __syncthreads();
    int* s = a; int* d = b;
    for (int off = 1; off < 512; off <<= 1) {
        int val = s[t];
        if (t >= off) val += s[t - off];
        d[t] = val;
        __syncthreads();
        int* tmp = s; s = d; d = tmp;
    }
    if (t < nb) bsum[t] = s[t] - v;
}

__global__ void scan_write_rowptr(const int* __restrict__ deg, const int* __restrict__ bsum,
                                  int* __restrict__ rowptr, float* __restrict__ dinv, int n) {
    __shared__ int a[BLK];
    __shared__ int b[BLK];
    int t = threadIdx.x;
    int i = blockIdx.x * BLK + t;
    int dgv = (i < n) ? deg[i] : 0;
    int v = (i < n) ? ((dgv + 7) & ~7) : 0;
    a[t] = v;
    __syncthreads();
    int* s = a; int* d = b;
    for (int off = 1; off < BLK; off <<= 1) {
        int val = s[t];
        if (t >= off) val += s[t - off];
        d[t] = val;
        __syncthreads();
        int* tmp = s; s = d; d = tmp;
    }
    if (i < n) {
        rowptr[i] = (s[t] - v) + bsum[blockIdx.x];
        dinv[i] = rsqrtf((float)(dgv + 1));
    }
}

// ---- GEMM body: Y[n+1][KOUT] fp16; optional dinv fold; pad-row n zeroed ---
template <int KOUT, bool HF32, bool FOLD>
__device__ __forceinline__ void gemm_body(int gb, const void* __restrict__ Hv,
                                          const unsigned short* __restrict__ Wt,
                                          const float* __restrict__ dinv,
                                          __half* __restrict__ Y, int n,
                                          unsigned short (*Hl)[72],
                                          unsigned short (*Wl)[72]) {
    const int t = threadIdx.x;
    const int row0 = gb * 64;
    const int wave = t >> 6, lane = t & 63;
    const int r16 = lane & 15, ko8 = (lane >> 4) * 8;

    if (gb == 0 && t < KOUT) Y[(size_t)n * KOUT + t] = __float2half(0.f);

    f32x4 acc[KOUT / 16];
#pragma unroll
    for (int c = 0; c < KOUT / 16; c++) acc[c] = (f32x4){0.f, 0.f, 0.f, 0.f};

#pragma unroll
    for (int h = 0; h < 2; h++) {
        if (h) __syncthreads();
        for (int idx = t; idx < KOUT * 8; idx += 256) {
            int r = idx >> 3, seg = idx & 7;
            *(uint4*)&Wl[r][seg * 8] = *(const uint4*)(Wt + r * 128 + h * 64 + seg * 8);
        }
        if (HF32) {
            const float* H = (const float*)Hv;
            for (int idx = t; idx < 64 * 8; idx += 256) {
                int r = idx >> 3, seg = idx & 7;
                int row = row0 + r;
                unsigned short tmp[8];
                if (row < n) {
                    const float* p = H + (size_t)row * 128 + h * 64 + seg * 8;
                    float4 v0 = *(const float4*)p, v1 = *(const float4*)(p + 4);
                    tmp[0] = f2bf(v0.x); tmp[1] = f2bf(v0.y); tmp[2] = f2bf(v0.z); tmp[3] = f2bf(v0.w);
                    tmp[4] = f2bf(v1.x); tmp[5] = f2bf(v1.y); tmp[6] = f2bf(v1.z); tmp[7] = f2bf(v1.w);
                } else {
#pragma unroll
                    for (int j = 0; j < 8; j++) tmp[j] = 0;
                }
                *(uint4*)&Hl[r][seg * 8] = *(const uint4*)tmp;
            }
        } else {
            const unsigned short* H = (const unsigned short*)Hv;
            for (int idx = t; idx < 64 * 8; idx += 256) {
                int r = idx >> 3, seg = idx & 7;
                int row = row0 + r;
                uint4 v = make_uint4(0, 0, 0, 0);
                if (row < n) v = *(const uint4*)(H + (size_t)row * 128 + h * 64 + seg * 8);
                *(uint4*)&Hl[r][seg * 8] = v;
            }
        }
        __syncthreads();
#pragma unroll
        for (int kc = 0; kc < 2; kc++) {
            bf16x8 a = *(const bf16x8*)&Hl[wave * 16 + r16][kc * 32 + ko8];
#pragma unroll
            for (int c = 0; c < KOUT / 16; c++) {
                bf16x8 bb = *(const bf16x8*)&Wl[c * 16 + r16][kc * 32 + ko8];
                acc[c] = __builtin_amdgcn_mfma_f32_16x16x32_bf16(a, bb, acc[c], 0, 0, 0);
            }
        }
    }

    const int mbase = row0 + wave * 16 + (lane >> 4) * 4;
#pragma unroll
    for (int r = 0; r < 4; r++) {
        int row = mbase + r;
        if (row < n) {
            float dv = FOLD ? dinv[row] : 1.f;
#pragma unroll
            for (int c = 0; c < KOUT / 16; c++)
                Y[(size_t)row * KOUT + c * 16 + r16] = __float2half_rn(acc[c][r] * dv);
        }
    }
}

// ---- megaB: [atomic-free place || gemm1 (x@Wt1, fold dinv)] ---------------
__global__ __launch_bounds__(256) void megaB(
    const int* __restrict__ src, const int* __restrict__ dst,
    const int* __restrict__ rnk, const int* __restrict__ rowptr,
    int* __restrict__ colidx, int E,
    const float* __restrict__ x, const unsigned short* __restrict__ Wt1,
    const float* __restrict__ dinv, __half* __restrict__ Y, int n, int nPlace) {
    __shared__ unsigned short Hl[64][72];
    __shared__ unsigned short Wl[128][72];
    const int b = blockIdx.x, t = threadIdx.x;
    if (b < nPlace) {
        int stride = nPlace * 256;
        for (int e = b * 256 + t; e < E; e += stride)
            colidx[rowptr[dst[e]] + rnk[e]] = src[e];
    } else {
        gemm_body<128, true, true>(b - nPlace, x, Wt1, dinv, Y, n, Hl, Wl);
    }
}

template <int KOUT>
__global__ __launch_bounds__(256) void gemm_std(const unsigned short* __restrict__ H,
                                                const unsigned short* __restrict__ Wt,
                                                __half* __restrict__ Y, int n) {
    __shared__ unsigned short Hl[64][72];
    __shared__ unsigned short Wl[KOUT][72];
    gemm_body<KOUT, false, false>(blockIdx.x, H, Wt, nullptr, Y, n, Hl, Wl);
}

// ---- agg KOUT=128 (R8 shape): quarter-wave per row, 4 edges/load-inst;
// Ys pre-scaled; epilogue relu + fold dinv -> bf16 Hb ----------------------
__global__ __launch_bounds__(256) void agg128(const __half* __restrict__ Ys,
                                              const int* __restrict__ deg,
                                              const float* __restrict__ dinv,
                                              const int* __restrict__ rowptr,
                                              const int* __restrict__ colidx,
                                              const float* __restrict__ bias,
                                              unsigned short* __restrict__ outb, int n) {
    int wid = (blockIdx.x * blockDim.x + threadIdx.x) >> 6;
    int lane = threadIdx.x & 63;
    if (wid >= n) return;
    const int q = lane >> 4;
    const int l4 = lane & 15;

    int start = __builtin_amdgcn_readfirstlane(rowptr[wid]);
    int m     = __builtin_amdgcn_readfirstlane(deg[wid]);   // indegree, no self
    int mpad  = (m + 7) & ~7;
    float di = dinv[wid];

    float acc[8];
#pragma unroll
    for (int j = 0; j < 8; j++) acc[j] = 0.f;
    if (q == 0) acc8(acc, Ys + ((size_t)wid << 7) + l4 * 8);  // self (pre-scaled)

    const int4* cp4 = (const int4*)(colidx + start);   // start % 8 == 0
    for (int j = 0; j < mpad; j += 8) {
        int4 a = cp4[j >> 2];
        int4 b = cp4[(j >> 2) + 1];
        int s0 = sel4(a, q), s1 = sel4(b, q);
        acc8(acc, Ys + ((size_t)s0 << 7) + l4 * 8);
        acc8(acc, Ys + ((size_t)s1 << 7) + l4 * 8);
    }
#pragma unroll
    for (int j = 0; j < 8; j++) {
        acc[j] += __shfl_xor(acc[j], 16);
        acc[j] += __shfl_xor(acc[j], 32);
    }

    if (q == 0) {
        float scale = di / (float)(m + 1);
        float4 b0 = *(const float4*)(bias + l4 * 8);
        float4 b1 = *(const float4*)(bias + l4 * 8 + 4);
        float o[8];
        o[0] = acc[0] * scale + b0.x; o[1] = acc[1] * scale + b0.y;
        o[2] = acc[2] * scale + b0.z; o[3] = acc[3] * scale + b0.w;
        o[4] = acc[4] * scale + b1.x; o[5] = acc[5] * scale + b1.y;
        o[6] = acc[6] * scale + b1.z; o[7] = acc[7] * scale + b1.w;
        unsigned short ob[8];
#pragma unroll
        for (int j = 0; j < 8; j++) ob[j] = f2bf(fmaxf(o[j], 0.f) * di);  // relu+fold
        *(uint4*)(outb + ((size_t)wid << 7) + l4 * 8) = *(const uint4*)ob;
    }
}

// ---- agg KOUT=64 (R8 shape): eighth-wave per row, 8 edges/load-inst; fp32 --
__global__ __launch_bounds__(256) void agg64(const __half* __restrict__ Ys,
                                             const int* __restrict__ deg,
                                             const float* __restrict__ dinv,
                                             const int* __restrict__ rowptr,
                                             const int* __restrict__ colidx,
                                             const float* __restrict__ bias,
                                             float* __restrict__ out, int n) {
    int wid = (blockIdx.x * blockDim.x + threadIdx.x) >> 6;
    int lane = threadIdx.x & 63;
    if (wid >= n) return;
    const int oct = lane >> 3;
    const int l3 = lane & 7;

    int start = __builtin_amdgcn_readfirstlane(rowptr[wid]);
    int m     = __builtin_amdgcn_readfirstlane(deg[wid]);
    int mpad  = (m + 7) & ~7;
    float di = dinv[wid];

    float acc[8];
#pragma unroll
    for (int j = 0; j < 8; j++) acc[j] = 0.f;
    if (oct == 0) acc8(acc, Ys + ((size_t)wid << 6) + l3 * 8);

    const int4* cp4 = (const int4*)(colidx + start);
    for (int j = 0; j < mpad; j += 8) {
        int4 a = cp4[j >> 2];
        int4 b = cp4[(j >> 2) + 1];
        int se = (oct < 4) ? sel4(a, oct) : sel4(b, oct - 4);
        acc8(acc, Ys + ((size_t)se << 6) + l3 * 8);
    }
#pragma unroll
    for (int j = 0; j < 8; j++) {
        acc[j] += __shfl_xor(acc[j], 8);
        acc[j] += __shfl_xor(acc[j], 16);
        acc[j] += __shfl_xor(acc[j], 32);
    }

    if (oct == 0) {
        float scale = di / (float)(m + 1);
        float4 b0 = *(const float4*)(bias + l3 * 8);
        float4 b1 = *(const float4*)(bias + l3 * 8 + 4);
        float o[8];
        o[0] = acc[0] * scale + b0.x; o[1] = acc[1] * scale + b0.y;
        o[2] = acc[2] * scale + b0.z; o[3] = acc[3] * scale + b0.w;
        o[4] = acc[4] * scale + b1.x; o[5] = acc[5] * scale + b1.y;
        o[6] = acc[6] * scale + b1.z; o[7] = acc[7] * scale + b1.w;
        float* op = out + ((size_t)wid << 6) + l3 * 8;
        *(float4*)op = make_float4(o[0], o[1], o[2], o[3]);
        *(float4*)(op + 4) = make_float4(o[4], o[5], o[6], o[7]);
    }
}

extern "C" void kernel_launch(void* const* d_in, const int* in_sizes, int n_in,
                              void* d_out, int out_size, void* d_ws, size_t ws_size,
                              hipStream_t stream) {
    const float* x  = (const float*)d_in[0];
    const int*   ei = (const int*)d_in[1];
    const float* W1 = (const float*)d_in[2];
    const float* b1 = (const float*)d_in[3];
    const float* W2 = (const float*)d_in[4];
    const float* b2 = (const float*)d_in[5];
    const float* W3 = (const float*)d_in[6];
    const float* b3 = (const float*)d_in[7];
    float* out = (float*)d_out;

    const int n = in_sizes[0] / 128;      // 100000
    const int E = in_sizes[1] / 2;        // 1600000
    const int* srcA = ei;
    const int* dstA = ei + E;
    const int Epad = E + 8 * n + 64;      // segments padded to 8 + slack

    // ---- workspace carve (aligned to 256B) ----
    auto alignup = [](size_t v) { return (v + 255) & ~(size_t)255; };
    char* base = (char*)d_ws;
    size_t off = 0;
    int* deg    = (int*)(base + off); off = alignup(off + (size_t)n * 4);
    int* rnk    = (int*)(base + off); off = alignup(off + (size_t)E * 4);
    int* rowptr = (int*)(base + off); off = alignup(off + (size_t)n * 4);
    int* bsum   = (int*)(base + off); off = alignup(off + (size_t)1024 * 4);
    int* colidx = (int*)(base + off); off = alignup(off + (size_t)Epad * 4);
    float* dinv = (float*)(base + off); off = alignup(off + (size_t)n * 4);
    unsigned short* Wt1 = (unsigned short*)(base + off); off = alignup(off + 16384 * 2);
    unsigned short* Wt2 = (unsigned short*)(base + off); off = alignup(off + 16384 * 2);
    unsigned short* Wt3 = (unsigned short*)(base + off); off = alignup(off + 8192 * 2);
    unsigned short* Hb  = (unsigned short*)(base + off); off = alignup(off + (size_t)n * 128 * 2);
    __half* Yb  = (__half*)(base + off); off = alignup(off + (size_t)(n + 1) * 128 * 2);
    (void)ws_size;

    const int nbN = (n + BLK - 1) / BLK;             // 391
    const int nCount = 2048, nInit = 256, nCast = 160;   // count needs full occupancy
    const int nPlace = 1024;
    const int nGemm = (n + 63) / 64;                 // 1563
    const int aggBlocks = (n * 64 + BLK - 1) / BLK;  // wave per node

    hipMemsetAsync(deg, 0, (size_t)n * 4, stream);

    // A: [count+rank || colidx init || Wt cast] — all LDS-free
    megaA<<<nCount + nInit + nCast, 256, 0, stream>>>(
        dstA, deg, rnk, E, colidx, Epad, n, W1, W2, W3, Wt1, Wt2, Wt3, nCount, nInit);

    // scans (rowptr = excl scan of roundup8(deg); dinv fused)
    scan_block_sums<<<nbN, BLK, 0, stream>>>(deg, bsum, n);
    scan_partials_excl<<<1, 512, 0, stream>>>(bsum, nbN);
    scan_write_rowptr<<<nbN, BLK, 0, stream>>>(deg, bsum, rowptr, dinv, n);

    // B: [place || gemm1 (x@Wt1, dinv folded)]
    megaB<<<nPlace + nGemm, 256, 0, stream>>>(
        srcA, dstA, rnk, rowptr, colidx, E, x, Wt1, dinv, Yb, n, nPlace);

    // layer 1 agg -> Hb bf16 (relu + fold dinv)
    agg128<<<aggBlocks, BLK, 0, stream>>>(Yb, deg, dinv, rowptr, colidx, b1, Hb, n);

    // layer 2
    gemm_std<128><<<nGemm, 256, 0, stream>>>(Hb, Wt2, Yb, n);
    agg128<<<aggBlocks, BLK, 0, stream>>>(Yb, deg, dinv, rowptr, colidx, b2, Hb, n);

    // layer 3 (KOUT=64, fp32 out, no relu)
    gemm_std<64><<<nGemm, 256, 0, stream>>>(Hb, Wt3, Yb, n);
    agg64<<<aggBlocks, BLK, 0, stream>>>(Yb, deg, dinv, rowptr, colidx, b3, out, n);
}